// Round 1
// baseline (462.548 us; speedup 1.0000x reference)
//
#include <hip/hip_runtime.h>
#include <hip/hip_bf16.h>

#define Dq 1024
#define Hq 4096
#define Eq 8
#define Tq 4096
#define BM 128
#define BN 128
#define BK 64
#define MAXTILES 40
#define HC_OFF 65536

// meta layout (ints): [0]=ntiles, [8..15]=counts, [16..24]=poff, [32..39]=cursor,
// [64..103]=tile_e, [128..167]=tile_row, [512..4607]=expert_id, [4608..9727]=perm
#define M_NT 0
#define M_CNT 8
#define M_POFF 16
#define M_CUR 32
#define M_TE 64
#define M_TR 128
#define M_EXP 512
#define M_PERM 4608

typedef __attribute__((ext_vector_type(8))) short bf16x8;
typedef __attribute__((ext_vector_type(4))) float f32x4;

__device__ __forceinline__ short f2bf(float f) {
    __hip_bfloat16 h = __float2bfloat16(f);
    return *reinterpret_cast<short*>(&h);
}

__device__ __forceinline__ int swz(int row, int c) {
    return c ^ ((row ^ (row >> 3)) & 7);
}

__device__ __forceinline__ float gelu_tanh(float x) {
    // 0.5*x*(1+tanh(u)) == x / (1 + exp(-2u)), u = sqrt(2/pi)*(x + 0.044715 x^3)
    float u = 0.7978845608028654f * (x + 0.044715f * x * x * x);
    return x / (1.0f + __expf(-2.0f * u));
}

__global__ void k_init(int* meta) {
    int i = blockIdx.x * 256 + threadIdx.x;
    if (i < M_PERM + MAXTILES * BM) meta[i] = 0;
}

__global__ void k_route(const float* __restrict__ x, const float* __restrict__ Wg,
                        const float* __restrict__ bg, int* meta) {
    int wave = threadIdx.x >> 6;
    int lane = threadIdx.x & 63;
    int t = blockIdx.x * 4 + wave;
    const float* xr = x + (size_t)t * Dq;
    float acc[8];
#pragma unroll
    for (int e = 0; e < 8; ++e) acc[e] = 0.0f;
#pragma unroll
    for (int j = 0; j < 16; ++j) {
        int d = j * 64 + lane;
        float xv = xr[d];
        float4 w0 = *(const float4*)(Wg + (size_t)d * 8);
        float4 w1 = *(const float4*)(Wg + (size_t)d * 8 + 4);
        acc[0] += xv * w0.x; acc[1] += xv * w0.y; acc[2] += xv * w0.z; acc[3] += xv * w0.w;
        acc[4] += xv * w1.x; acc[5] += xv * w1.y; acc[6] += xv * w1.z; acc[7] += xv * w1.w;
    }
#pragma unroll
    for (int e = 0; e < 8; ++e) {
#pragma unroll
        for (int off = 32; off > 0; off >>= 1) acc[e] += __shfl_xor(acc[e], off);
    }
    if (lane == 0) {
        float best = acc[0] + bg[0];
        int be = 0;
#pragma unroll
        for (int e = 1; e < 8; ++e) {
            float v = acc[e] + bg[e];
            if (v > best) { best = v; be = e; }
        }
        meta[M_EXP + t] = be;
        atomicAdd(&meta[M_CNT + be], 1);
    }
}

__global__ void k_scan(int* meta) {
    if (threadIdx.x != 0) return;
    int off = 0, nt = 0;
    for (int e = 0; e < 8; ++e) {
        meta[M_POFF + e] = off;
        int c = meta[M_CNT + e];
        int m = (c + BM - 1) / BM;
        for (int j = 0; j < m; ++j) {
            meta[M_TE + nt] = e;
            meta[M_TR + nt] = off + j * BM;
            ++nt;
        }
        off += m * BM;
    }
    meta[M_POFF + 8] = off;
    meta[M_NT] = nt;
}

__global__ void k_scatter(int* meta) {
    int t = blockIdx.x * 256 + threadIdx.x;
    if (t >= Tq) return;
    int e = meta[M_EXP + t];
    int pos = atomicAdd(&meta[M_CUR + e], 1);
    meta[M_PERM + meta[M_POFF + e] + pos] = t;
}

// GEMM1: Hc[i, h] = gelu( sum_d x[perm[i], d] * W1[e, d, h] ), bf16 out
__global__ __launch_bounds__(256, 2) void k_gemm1(const float* __restrict__ x,
                                                  const float* __restrict__ W1,
                                                  const int* __restrict__ meta,
                                                  short* __restrict__ Hc) {
    __shared__ short As[BM * BK];
    __shared__ short Bs[BN * BK];
    int mt = blockIdx.x;
    if (mt >= meta[M_NT]) return;
    int e = meta[M_TE + mt];
    int i0 = meta[M_TR + mt];
    int n0 = blockIdx.y * BN;
    int tt = threadIdx.x;
    const int* perm = meta + M_PERM;

    int arow = tt & 127;
    int tok = perm[i0 + arow];
    const float* xr = x + (size_t)tok * Dq;
    int acg = (tt >> 7) * 4;

    int bn4 = (tt & 31) * 4;
    int bkg = tt >> 5;
    const float* wbase = W1 + ((size_t)e * Dq + (size_t)bkg * 8) * Hq + n0 + bn4;

    f32x4 zero = {0.f, 0.f, 0.f, 0.f};
    f32x4 acc[4][4];
#pragma unroll
    for (int a = 0; a < 4; ++a)
#pragma unroll
        for (int b = 0; b < 4; ++b) acc[a][b] = zero;

    int wave = tt >> 6, lane = tt & 63;
    int wm = (wave >> 1) * 64, wn = (wave & 1) * 64;

    for (int kb = 0; kb < Dq; kb += BK) {
        // stage A (tokens, fp32 -> bf16), rows contiguous in K
#pragma unroll
        for (int i = 0; i < 4; ++i) {
            int c = acg + i;
            float4 f0 = *(const float4*)(xr + kb + c * 8);
            float4 f1 = *(const float4*)(xr + kb + c * 8 + 4);
            bf16x8 v;
            v[0] = f2bf(f0.x); v[1] = f2bf(f0.y); v[2] = f2bf(f0.z); v[3] = f2bf(f0.w);
            v[4] = f2bf(f1.x); v[5] = f2bf(f1.y); v[6] = f2bf(f1.z); v[7] = f2bf(f1.w);
            *(bf16x8*)(&As[arow * BK + swz(arow, c) * 8]) = v;
        }
        // stage B (W1 is [K][N]; transpose to [n][k] in LDS, fp32 -> bf16)
        float wvf[32];
#pragma unroll
        for (int r = 0; r < 8; ++r) {
            float4 tv = *(const float4*)(wbase + (size_t)(kb + r) * Hq);
            wvf[r * 4 + 0] = tv.x; wvf[r * 4 + 1] = tv.y;
            wvf[r * 4 + 2] = tv.z; wvf[r * 4 + 3] = tv.w;
        }
#pragma unroll
        for (int j = 0; j < 4; ++j) {
            bf16x8 v;
#pragma unroll
            for (int r = 0; r < 8; ++r) v[r] = f2bf(wvf[r * 4 + j]);
            int n = bn4 + j;
            *(bf16x8*)(&Bs[n * BK + swz(n, bkg) * 8]) = v;
        }
        __syncthreads();
#pragma unroll
        for (int kk = 0; kk < 2; ++kk) {
            bf16x8 af[4], bfr[4];
#pragma unroll
            for (int f = 0; f < 4; ++f) {
                int r = wm + f * 16 + (lane & 15);
                int c = kk * 4 + (lane >> 4);
                af[f] = *(const bf16x8*)(&As[r * BK + swz(r, c) * 8]);
                int rb = wn + f * 16 + (lane & 15);
                bfr[f] = *(const bf16x8*)(&Bs[rb * BK + swz(rb, c) * 8]);
            }
#pragma unroll
            for (int fm = 0; fm < 4; ++fm)
#pragma unroll
                for (int fn = 0; fn < 4; ++fn)
                    acc[fm][fn] = __builtin_amdgcn_mfma_f32_16x16x32_bf16(
                        af[fm], bfr[fn], acc[fm][fn], 0, 0, 0);
        }
        __syncthreads();
    }
    // epilogue: gelu, store bf16 to Hc (padded rows get valid token-0 data; never combined)
#pragma unroll
    for (int fm = 0; fm < 4; ++fm) {
        int rbase = i0 + wm + fm * 16 + ((lane >> 4) << 2);
#pragma unroll
        for (int fn = 0; fn < 4; ++fn) {
            int col = n0 + wn + fn * 16 + (lane & 15);
#pragma unroll
            for (int q = 0; q < 4; ++q) {
                float v = gelu_tanh(acc[fm][fn][q]);
                Hc[(size_t)(rbase + q) * Hq + col] = f2bf(v);
            }
        }
    }
}

// GEMM2: out[perm[i], d] = sum_h Hc[i, h] * W2[e, h, d]
__global__ __launch_bounds__(256, 2) void k_gemm2(const short* __restrict__ Hc,
                                                  const float* __restrict__ W2,
                                                  const int* __restrict__ meta,
                                                  float* __restrict__ out) {
    __shared__ short As[BM * BK];
    __shared__ short Bs[BN * BK];
    int mt = blockIdx.x;
    if (mt >= meta[M_NT]) return;
    int e = meta[M_TE + mt];
    int i0 = meta[M_TR + mt];
    int n0 = blockIdx.y * BN;
    int tt = threadIdx.x;
    const int* perm = meta + M_PERM;
    int vend = meta[M_POFF + e] + meta[M_CNT + e];

    int arow = tt & 127;
    const short* hr = Hc + (size_t)(i0 + arow) * Hq;
    int acg = (tt >> 7) * 4;

    int bn4 = (tt & 31) * 4;
    int bkg = tt >> 5;
    const float* wbase = W2 + ((size_t)e * Hq + (size_t)bkg * 8) * Dq + n0 + bn4;

    f32x4 zero = {0.f, 0.f, 0.f, 0.f};
    f32x4 acc[4][4];
#pragma unroll
    for (int a = 0; a < 4; ++a)
#pragma unroll
        for (int b = 0; b < 4; ++b) acc[a][b] = zero;

    int wave = tt >> 6, lane = tt & 63;
    int wm = (wave >> 1) * 64, wn = (wave & 1) * 64;

    for (int kb = 0; kb < Hq; kb += BK) {
        // stage A (Hc already bf16, contiguous)
#pragma unroll
        for (int i = 0; i < 4; ++i) {
            int c = acg + i;
            bf16x8 v = *(const bf16x8*)(hr + kb + c * 8);
            *(bf16x8*)(&As[arow * BK + swz(arow, c) * 8]) = v;
        }
        // stage B (W2 [K][N] -> LDS [n][k], fp32 -> bf16)
        float wvf[32];
#pragma unroll
        for (int r = 0; r < 8; ++r) {
            float4 tv = *(const float4*)(wbase + (size_t)(kb + r) * Dq);
            wvf[r * 4 + 0] = tv.x; wvf[r * 4 + 1] = tv.y;
            wvf[r * 4 + 2] = tv.z; wvf[r * 4 + 3] = tv.w;
        }
#pragma unroll
        for (int j = 0; j < 4; ++j) {
            bf16x8 v;
#pragma unroll
            for (int r = 0; r < 8; ++r) v[r] = f2bf(wvf[r * 4 + j]);
            int n = bn4 + j;
            *(bf16x8*)(&Bs[n * BK + swz(n, bkg) * 8]) = v;
        }
        __syncthreads();
#pragma unroll
        for (int kk = 0; kk < 2; ++kk) {
            bf16x8 af[4], bfr[4];
#pragma unroll
            for (int f = 0; f < 4; ++f) {
                int r = wm + f * 16 + (lane & 15);
                int c = kk * 4 + (lane >> 4);
                af[f] = *(const bf16x8*)(&As[r * BK + swz(r, c) * 8]);
                int rb = wn + f * 16 + (lane & 15);
                bfr[f] = *(const bf16x8*)(&Bs[rb * BK + swz(rb, c) * 8]);
            }
#pragma unroll
            for (int fm = 0; fm < 4; ++fm)
#pragma unroll
                for (int fn = 0; fn < 4; ++fn)
                    acc[fm][fn] = __builtin_amdgcn_mfma_f32_16x16x32_bf16(
                        af[fm], bfr[fn], acc[fm][fn], 0, 0, 0);
        }
        __syncthreads();
    }
    // epilogue: scatter valid rows to out (fp32)
#pragma unroll
    for (int fm = 0; fm < 4; ++fm) {
        int rbase = i0 + wm + fm * 16 + ((lane >> 4) << 2);
#pragma unroll
        for (int q = 0; q < 4; ++q) {
            int i = rbase + q;
            if (i < vend) {
                int tok = perm[i];
#pragma unroll
                for (int fn = 0; fn < 4; ++fn) {
                    int col = n0 + wn + fn * 16 + (lane & 15);
                    out[(size_t)tok * Dq + col] = acc[fm][fn][q];
                }
            }
        }
    }
}

extern "C" void kernel_launch(void* const* d_in, const int* in_sizes, int n_in,
                              void* d_out, int out_size, void* d_ws, size_t ws_size,
                              hipStream_t stream) {
    const float* x  = (const float*)d_in[0];
    const float* W1 = (const float*)d_in[1];
    const float* W2 = (const float*)d_in[2];
    const float* Wg = (const float*)d_in[3];
    const float* bg = (const float*)d_in[4];
    float* out = (float*)d_out;
    int* meta = (int*)d_ws;
    short* Hc = (short*)((char*)d_ws + HC_OFF);

    k_init<<<38, 256, 0, stream>>>(meta);
    k_route<<<Tq / 4, 256, 0, stream>>>(x, Wg, bg, meta);
    k_scan<<<1, 64, 0, stream>>>(meta);
    k_scatter<<<Tq / 256, 256, 0, stream>>>(meta);
    dim3 g1(MAXTILES, Hq / BN);
    k_gemm1<<<g1, 256, 0, stream>>>(x, W1, meta, Hc);
    dim3 g2(MAXTILES, Dq / BN);
    k_gemm2<<<g2, 256, 0, stream>>>(Hc, W2, meta, out);
}

// Round 2
// 342.353 us; speedup vs baseline: 1.3511x; 1.3511x over previous
//
#include <hip/hip_runtime.h>
#include <hip/hip_bf16.h>

#define Dq 1024
#define Hq 4096
#define Eq 8
#define Tq 4096
#define BM 128
#define BN 128
#define BN2 64
#define BK 64
#define MAXTILES 40
#define XB_OFF 65536
#define HC_OFF (65536 + 8388608)

// meta layout (ints)
#define M_NT 0
#define M_CNT 8
#define M_POFF 16
#define M_CUR 32
#define M_TE 64
#define M_TR 128
#define M_EXP 512
#define M_PERM 4608

typedef __attribute__((ext_vector_type(8))) short bf16x8;
typedef __attribute__((ext_vector_type(4))) short bf16x4;
typedef __attribute__((ext_vector_type(4))) float f32x4;

__device__ __forceinline__ short f2bf(float f) {
    __hip_bfloat16 h = __float2bfloat16(f);
    return *reinterpret_cast<short*>(&h);
}

__device__ __forceinline__ int swz(int row, int c) {
    return c ^ ((row ^ (row >> 3)) & 7);
}

__device__ __forceinline__ float gelu_tanh(float x) {
    float u = 0.7978845608028654f * (x + 0.044715f * x * x * x);
    return x / (1.0f + __expf(-2.0f * u));
}

typedef __attribute__((address_space(1))) const void gvoid;
typedef __attribute__((address_space(3))) void lvoid;
__device__ __forceinline__ void glds16(const void* g, void* l) {
    __builtin_amdgcn_global_load_lds((gvoid*)g, (lvoid*)l, 16, 0, 0);
}

__global__ void k_init(int* meta) {
    int i = blockIdx.x * 256 + threadIdx.x;
    if (i < M_PERM + MAXTILES * BM) meta[i] = 0;
}

// x fp32 -> xb bf16 (straight copy/convert, row-major [Tq][Dq])
__global__ void k_conv(const float* __restrict__ x, short* __restrict__ xb) {
    int t = blockIdx.x * 256 + threadIdx.x;
    size_t base = (size_t)t * 8;
    float4 f0 = *(const float4*)(x + base);
    float4 f1 = *(const float4*)(x + base + 4);
    bf16x8 v;
    v[0] = f2bf(f0.x); v[1] = f2bf(f0.y); v[2] = f2bf(f0.z); v[3] = f2bf(f0.w);
    v[4] = f2bf(f1.x); v[5] = f2bf(f1.y); v[6] = f2bf(f1.z); v[7] = f2bf(f1.w);
    *(bf16x8*)(xb + base) = v;
}

__global__ void k_route(const float* __restrict__ x, const float* __restrict__ Wg,
                        const float* __restrict__ bg, int* meta) {
    int wave = threadIdx.x >> 6;
    int lane = threadIdx.x & 63;
    int t = blockIdx.x * 4 + wave;
    const float* xr = x + (size_t)t * Dq;
    float acc[8];
#pragma unroll
    for (int e = 0; e < 8; ++e) acc[e] = 0.0f;
#pragma unroll
    for (int j = 0; j < 16; ++j) {
        int d = j * 64 + lane;
        float xv = xr[d];
        float4 w0 = *(const float4*)(Wg + (size_t)d * 8);
        float4 w1 = *(const float4*)(Wg + (size_t)d * 8 + 4);
        acc[0] += xv * w0.x; acc[1] += xv * w0.y; acc[2] += xv * w0.z; acc[3] += xv * w0.w;
        acc[4] += xv * w1.x; acc[5] += xv * w1.y; acc[6] += xv * w1.z; acc[7] += xv * w1.w;
    }
#pragma unroll
    for (int e = 0; e < 8; ++e) {
#pragma unroll
        for (int off = 32; off > 0; off >>= 1) acc[e] += __shfl_xor(acc[e], off);
    }
    if (lane == 0) {
        float best = acc[0] + bg[0];
        int be = 0;
#pragma unroll
        for (int e = 1; e < 8; ++e) {
            float v = acc[e] + bg[e];
            if (v > best) { best = v; be = e; }
        }
        meta[M_EXP + t] = be;
        atomicAdd(&meta[M_CNT + be], 1);
    }
}

__global__ void k_scan(int* meta) {
    if (threadIdx.x != 0) return;
    int off = 0, nt = 0;
    for (int e = 0; e < 8; ++e) {
        meta[M_POFF + e] = off;
        int c = meta[M_CNT + e];
        int m = (c + BM - 1) / BM;
        for (int j = 0; j < m; ++j) {
            meta[M_TE + nt] = e;
            meta[M_TR + nt] = off + j * BM;
            ++nt;
        }
        off += m * BM;
    }
    meta[M_POFF + 8] = off;
    meta[M_NT] = nt;
}

__global__ void k_scatter(int* meta) {
    int t = blockIdx.x * 256 + threadIdx.x;
    if (t >= Tq) return;
    int e = meta[M_EXP + t];
    int pos = atomicAdd(&meta[M_CUR + e], 1);
    meta[M_PERM + meta[M_POFF + e] + pos] = t;
}

// ---------------- GEMM1: Hc[i,h] = gelu(sum_d xb[perm[i],d] * W1[e,d,h]) ----------------
// pipeline step: cvt+write B(cur); syncthreads (drains glds A[cur]); prefetch next
// (B regs + glds A[nxt]); ds_read + MFMA on cur; raw s_barrier (WAR only).
#define G1_STEP(brC, brN, CB, NB, KBN, PREF)                                     \
  {                                                                              \
    _Pragma("unroll")                                                            \
    for (int j = 0; j < 4; ++j) {                                                \
      bf16x8 v;                                                                  \
      _Pragma("unroll")                                                          \
      for (int r = 0; r < 8; ++r) v[r] = f2bf(((const float*)&brC[r])[j]);       \
      int n = bn4 + j;                                                           \
      *(bf16x8*)(&Bs[n * BK + swz(n, bkg) * 8]) = v;                             \
    }                                                                            \
    __syncthreads();                                                             \
    if (PREF) {                                                                  \
      _Pragma("unroll")                                                          \
      for (int r = 0; r < 8; ++r)                                                \
        brN[r] = *(const float4*)(wbase + (size_t)((KBN) + r) * Hq);             \
      _Pragma("unroll")                                                          \
      for (int s = 0; s < 4; ++s)                                                \
        glds16(asrc[s] + (KBN), &As[(NB) * 8192 + ldsoff[s]]);                   \
    }                                                                            \
    _Pragma("unroll")                                                            \
    for (int kk = 0; kk < 2; ++kk) {                                             \
      bf16x8 af[4], bfv[4];                                                      \
      _Pragma("unroll")                                                          \
      for (int f = 0; f < 4; ++f) {                                              \
        int r = wm + f * 16 + (lane & 15);                                       \
        int cA = kk * 4 + (lane >> 4);                                           \
        af[f] = *(const bf16x8*)(&As[(CB) * 8192 + (r * 8 + (cA ^ (r & 7))) * 8]); \
        int rb = wn + f * 16 + (lane & 15);                                      \
        bfv[f] = *(const bf16x8*)(&Bs[rb * BK + swz(rb, cA) * 8]);               \
      }                                                                          \
      _Pragma("unroll")                                                          \
      for (int fm = 0; fm < 4; ++fm)                                             \
        _Pragma("unroll")                                                        \
        for (int fn = 0; fn < 4; ++fn)                                           \
          acc[fm][fn] = __builtin_amdgcn_mfma_f32_16x16x32_bf16(                 \
              af[fm], bfv[fn], acc[fm][fn], 0, 0, 0);                            \
    }                                                                            \
    __builtin_amdgcn_s_barrier();                                                \
    __builtin_amdgcn_sched_barrier(0);                                           \
  }

__global__ __launch_bounds__(256, 2) void k_gemm1(const short* __restrict__ xb,
                                                  const float* __restrict__ W1,
                                                  const int* __restrict__ meta,
                                                  short* __restrict__ Hc) {
    __shared__ short As[2 * 8192];
    __shared__ short Bs[BN * BK];
    int mt = blockIdx.x;
    if (mt >= meta[M_NT]) return;
    int e = meta[M_TE + mt];
    int i0 = meta[M_TR + mt];
    int n0 = blockIdx.y * BN;
    int tt = threadIdx.x;
    int wave = tt >> 6, lane = tt & 63;
    const int* perm = meta + M_PERM;

    // A glds: slot s covers rows [s*32 + wave*8, +8); lane -> row +(lane>>3), chunk c=(lane&7)^(lane>>3)
    int rlo = lane >> 3;
    int cc = (lane & 7) ^ rlo;
    const short* asrc[4];
    int ldsoff[4];
#pragma unroll
    for (int s = 0; s < 4; ++s) {
        int row = s * 32 + wave * 8 + rlo;
        int prow = perm[i0 + row];
        asrc[s] = xb + (size_t)prow * Dq + cc * 8;
        ldsoff[s] = (s * 4 + wave) * 512;  // shorts
    }

    int bn4 = (tt & 31) * 4;
    int bkg = tt >> 5;
    const float* wbase = W1 + ((size_t)e * Dq + (size_t)bkg * 8) * Hq + n0 + bn4;

    int wm = (wave >> 1) * 64, wn = (wave & 1) * 64;

    f32x4 acc[4][4];
#pragma unroll
    for (int a = 0; a < 4; ++a)
#pragma unroll
        for (int b = 0; b < 4; ++b) acc[a][b] = (f32x4){0.f, 0.f, 0.f, 0.f};

    // prologue: chunk 0 in flight
    float4 br0[8], br1[8];
#pragma unroll
    for (int r = 0; r < 8; ++r) br0[r] = *(const float4*)(wbase + (size_t)r * Hq);
#pragma unroll
    for (int s = 0; s < 4; ++s) glds16(asrc[s], &As[ldsoff[s]]);

    for (int kb = 0; kb < Dq; kb += 2 * BK) {
        G1_STEP(br0, br1, 0, 1, kb + BK, true)
        G1_STEP(br1, br0, 1, 0, kb + 2 * BK, (kb + 2 * BK) < Dq)
    }

    // epilogue: gelu -> bf16 Hc
#pragma unroll
    for (int fm = 0; fm < 4; ++fm) {
        int rbase = i0 + wm + fm * 16 + ((lane >> 4) << 2);
#pragma unroll
        for (int fn = 0; fn < 4; ++fn) {
            int col = n0 + wn + fn * 16 + (lane & 15);
#pragma unroll
            for (int q = 0; q < 4; ++q) {
                float v = gelu_tanh(acc[fm][fn][q]);
                Hc[(size_t)(rbase + q) * Hq + col] = f2bf(v);
            }
        }
    }
}

// ---------------- GEMM2: out[perm[i],d] = sum_h Hc[i,h] * W2[e,h,d] ----------------
#define G2_STEP(brC, brN, CB, NB, KBN, PREF)                                     \
  {                                                                              \
    _Pragma("unroll")                                                            \
    for (int j = 0; j < 4; ++j) {                                                \
      bf16x4 v;                                                                  \
      _Pragma("unroll")                                                          \
      for (int r = 0; r < 4; ++r) v[r] = f2bf(((const float*)&brC[r])[j]);       \
      int n = bn4 + j;                                                           \
      *(bf16x4*)(&Bs2[n * BK + swz(n, kc) * 8 + sub4]) = v;                      \
    }                                                                            \
    __syncthreads();                                                             \
    if (PREF) {                                                                  \
      _Pragma("unroll")                                                          \
      for (int r = 0; r < 4; ++r)                                                \
        brN[r] = *(const float4*)(wbase + (size_t)((KBN) + r) * Dq);             \
      _Pragma("unroll")                                                          \
      for (int s = 0; s < 4; ++s)                                                \
        glds16(asrc[s] + (KBN), &As[(NB) * 8192 + ldsoff[s]]);                   \
    }                                                                            \
    _Pragma("unroll")                                                            \
    for (int kk = 0; kk < 2; ++kk) {                                             \
      bf16x8 af[4], bfv[2];                                                      \
      _Pragma("unroll")                                                          \
      for (int f = 0; f < 4; ++f) {                                              \
        int r = wm + f * 16 + (lane & 15);                                       \
        int cA = kk * 4 + (lane >> 4);                                           \
        af[f] = *(const bf16x8*)(&As[(CB) * 8192 + (r * 8 + (cA ^ (r & 7))) * 8]); \
      }                                                                          \
      _Pragma("unroll")                                                          \
      for (int f = 0; f < 2; ++f) {                                              \
        int rb = wn + f * 16 + (lane & 15);                                      \
        int cA = kk * 4 + (lane >> 4);                                           \
        bfv[f] = *(const bf16x8*)(&Bs2[rb * BK + swz(rb, cA) * 8]);              \
      }                                                                          \
      _Pragma("unroll")                                                          \
      for (int fm = 0; fm < 4; ++fm)                                             \
        _Pragma("unroll")                                                        \
        for (int fn = 0; fn < 2; ++fn)                                           \
          acc[fm][fn] = __builtin_amdgcn_mfma_f32_16x16x32_bf16(                 \
              af[fm], bfv[fn], acc[fm][fn], 0, 0, 0);                            \
    }                                                                            \
    __builtin_amdgcn_s_barrier();                                                \
    __builtin_amdgcn_sched_barrier(0);                                           \
  }

__global__ __launch_bounds__(256, 2) void k_gemm2(const short* __restrict__ Hc,
                                                  const float* __restrict__ W2,
                                                  const int* __restrict__ meta,
                                                  float* __restrict__ out) {
    __shared__ short As[2 * 8192];
    __shared__ short Bs2[BN2 * BK];
    int mt = blockIdx.x;
    if (mt >= meta[M_NT]) return;
    int e = meta[M_TE + mt];
    int i0 = meta[M_TR + mt];
    int n0 = blockIdx.y * BN2;
    int tt = threadIdx.x;
    int wave = tt >> 6, lane = tt & 63;
    const int* perm = meta + M_PERM;
    int vend = meta[M_POFF + e] + meta[M_CNT + e];

    int rlo = lane >> 3;
    int cc = (lane & 7) ^ rlo;
    const short* asrc[4];
    int ldsoff[4];
#pragma unroll
    for (int s = 0; s < 4; ++s) {
        int row = s * 32 + wave * 8 + rlo;
        asrc[s] = Hc + (size_t)(i0 + row) * Hq + cc * 8;
        ldsoff[s] = (s * 4 + wave) * 512;
    }

    // B: 64n x 64k; thread covers k-rows [bkg*4,+4) at n cols [bn4,+4)
    int bn4 = (tt & 15) * 4;
    int bkg = tt >> 4;  // 0..15
    int kc = bkg >> 1;
    int sub4 = (bkg & 1) * 4;
    const float* wbase = W2 + ((size_t)e * Hq + (size_t)bkg * 4) * Dq + n0 + bn4;

    int wm = (wave >> 1) * 64, wn = (wave & 1) * 32;

    f32x4 acc[4][2];
#pragma unroll
    for (int a = 0; a < 4; ++a)
#pragma unroll
        for (int b = 0; b < 2; ++b) acc[a][b] = (f32x4){0.f, 0.f, 0.f, 0.f};

    float4 br0[4], br1[4];
#pragma unroll
    for (int r = 0; r < 4; ++r) br0[r] = *(const float4*)(wbase + (size_t)r * Dq);
#pragma unroll
    for (int s = 0; s < 4; ++s) glds16(asrc[s], &As[ldsoff[s]]);

    for (int kb = 0; kb < Hq; kb += 2 * BK) {
        G2_STEP(br0, br1, 0, 1, kb + BK, true)
        G2_STEP(br1, br0, 1, 0, kb + 2 * BK, (kb + 2 * BK) < Hq)
    }

#pragma unroll
    for (int fm = 0; fm < 4; ++fm) {
        int rbase = i0 + wm + fm * 16 + ((lane >> 4) << 2);
#pragma unroll
        for (int q = 0; q < 4; ++q) {
            int i = rbase + q;
            if (i < vend) {
                int tok = perm[i];
#pragma unroll
                for (int fn = 0; fn < 2; ++fn) {
                    int col = n0 + wn + fn * 16 + (lane & 15);
                    out[(size_t)tok * Dq + col] = acc[fm][fn][q];
                }
            }
        }
    }
}

extern "C" void kernel_launch(void* const* d_in, const int* in_sizes, int n_in,
                              void* d_out, int out_size, void* d_ws, size_t ws_size,
                              hipStream_t stream) {
    const float* x  = (const float*)d_in[0];
    const float* W1 = (const float*)d_in[1];
    const float* W2 = (const float*)d_in[2];
    const float* Wg = (const float*)d_in[3];
    const float* bg = (const float*)d_in[4];
    float* out = (float*)d_out;
    int* meta = (int*)d_ws;
    short* xb = (short*)((char*)d_ws + XB_OFF);
    short* Hc = (short*)((char*)d_ws + HC_OFF);

    k_init<<<38, 256, 0, stream>>>(meta);
    k_conv<<<(Tq * Dq / 8) / 256, 256, 0, stream>>>(x, xb);
    k_route<<<Tq / 4, 256, 0, stream>>>(x, Wg, bg, meta);
    k_scan<<<1, 64, 0, stream>>>(meta);
    k_scatter<<<Tq / 256, 256, 0, stream>>>(meta);
    dim3 g1(MAXTILES, Hq / BN);
    k_gemm1<<<g1, 256, 0, stream>>>(xb, W1, meta, Hc);
    dim3 g2(MAXTILES, Dq / BN2);
    k_gemm2<<<g2, 256, 0, stream>>>(Hc, W2, meta, out);
}